// Round 4
// baseline (155.321 us; speedup 1.0000x reference)
//
#include <hip/hip_runtime.h>
#include <hip/hip_bf16.h>

#define NFEA 128
#define NCLS 5
#define LN_EPS 1e-5f
#define CHUNK 1024   // atoms per block-owned chunk

// LN -> softplus -> head for one crystal, executed by one 64-lane wave.
// lane holds features (lane) and (lane+64) as p0/p1 (already mean-divided).
__device__ __forceinline__ void finalize_crystal(
    int lane, int c, float p0, float p1,
    const float* __restrict__ lnw, const float* __restrict__ lnb,
    const float* __restrict__ outw, const float* __restrict__ outb,
    float* __restrict__ out_cls, float* __restrict__ out_act)
{
    float t = p0 + p1;
    #pragma unroll
    for (int off = 32; off; off >>= 1) t += __shfl_xor(t, off);
    const float mu = t * (1.f / NFEA);

    const float d0 = p0 - mu, d1 = p1 - mu;
    float v = d0 * d0 + d1 * d1;
    #pragma unroll
    for (int off = 32; off; off >>= 1) v += __shfl_xor(v, off);
    const float rstd = rsqrtf(v * (1.f / NFEA) + LN_EPS);

    const float x0 = d0 * rstd * lnw[lane]      + lnb[lane];
    const float x1 = d1 * rstd * lnw[lane + 64] + lnb[lane + 64];
    const float a0 = (x0 > 0.f) ? x0 + log1pf(expf(-x0)) : log1pf(expf(x0));
    const float a1 = (x1 > 0.f) ? x1 + log1pf(expf(-x1)) : log1pf(expf(x1));

    out_act[(size_t)c * NFEA + lane]      = a0;
    out_act[(size_t)c * NFEA + lane + 64] = a1;

    #pragma unroll
    for (int k = 0; k < NCLS; ++k) {
        float p = a0 * outw[k * NFEA + lane] + a1 * outw[k * NFEA + lane + 64];
        #pragma unroll
        for (int off = 32; off; off >>= 1) p += __shfl_xor(p, off);
        if (lane == k) out_cls[(size_t)c * NCLS + k] = p + outb[k];
    }
}

// Kernel A: each block streams a 1024-atom chunk (8 atom-lanes x 32 float4 cols).
// Interior crystals (fully inside the chunk) are finalized in place by wave 0
// (overlapped with the next run's loads). Straddlers atomicAdd into seg_sum.
__global__ __launch_bounds__(256) void fused_pool_kernel(
    const float* __restrict__ fea,      // [N_ATOMS][128]
    const int2*  __restrict__ idx,      // [N_CRYS]
    float* __restrict__ seg_sum,        // [N_CRYS][128], zeroed
    const float* __restrict__ lnw, const float* __restrict__ lnb,
    const float* __restrict__ outw, const float* __restrict__ outb,
    float* __restrict__ out_cls, float* __restrict__ out_act,
    int n_crys)
{
    const int c0 = blockIdx.x * CHUNK;
    const int c1 = c0 + CHUNK;          // N_ATOMS % CHUNK == 0
    const int tid = threadIdx.x;
    const int fc  = tid & 31;
    const int al  = tid >> 5;

    // largest s with idx[s].x <= c0
    int lo = 0, hi = n_crys - 1;
    while (lo < hi) {
        int mid = (lo + hi + 1) >> 1;
        if (idx[mid].x <= c0) lo = mid; else hi = mid - 1;
    }
    int s = lo;

    const float4* __restrict__ fea4 = (const float4*)fea;
    __shared__ float4 red4[8][32];
    __shared__ float pooledA[NFEA];

    int rs = c0;
    while (rs < c1) {
        const int2 se = idx[s];
        const int re = min(se.y, c1);

        float4 acc0 = make_float4(0.f,0.f,0.f,0.f);
        float4 acc1 = make_float4(0.f,0.f,0.f,0.f);
        float4 acc2 = make_float4(0.f,0.f,0.f,0.f);
        float4 acc3 = make_float4(0.f,0.f,0.f,0.f);

        int a = rs + al;
        if (a + 24 < re) {
            float4 v0 = fea4[(size_t)a        * 32 + fc];
            float4 v1 = fea4[(size_t)(a + 8)  * 32 + fc];
            float4 v2 = fea4[(size_t)(a + 16) * 32 + fc];
            float4 v3 = fea4[(size_t)(a + 24) * 32 + fc];
            a += 32;
            for (; a + 24 < re; a += 32) {
                float4 n0 = fea4[(size_t)a        * 32 + fc];
                float4 n1 = fea4[(size_t)(a + 8)  * 32 + fc];
                float4 n2 = fea4[(size_t)(a + 16) * 32 + fc];
                float4 n3 = fea4[(size_t)(a + 24) * 32 + fc];
                acc0.x += v0.x; acc0.y += v0.y; acc0.z += v0.z; acc0.w += v0.w;
                acc1.x += v1.x; acc1.y += v1.y; acc1.z += v1.z; acc1.w += v1.w;
                acc2.x += v2.x; acc2.y += v2.y; acc2.z += v2.z; acc2.w += v2.w;
                acc3.x += v3.x; acc3.y += v3.y; acc3.z += v3.z; acc3.w += v3.w;
                v0 = n0; v1 = n1; v2 = n2; v3 = n3;
            }
            acc0.x += v0.x; acc0.y += v0.y; acc0.z += v0.z; acc0.w += v0.w;
            acc1.x += v1.x; acc1.y += v1.y; acc1.z += v1.z; acc1.w += v1.w;
            acc2.x += v2.x; acc2.y += v2.y; acc2.z += v2.z; acc2.w += v2.w;
            acc3.x += v3.x; acc3.y += v3.y; acc3.z += v3.z; acc3.w += v3.w;
        }
        for (; a < re; a += 8) {
            float4 v = fea4[(size_t)a * 32 + fc];
            acc0.x += v.x; acc0.y += v.y; acc0.z += v.z; acc0.w += v.w;
        }
        acc0.x += acc1.x + acc2.x + acc3.x;
        acc0.y += acc1.y + acc2.y + acc3.y;
        acc0.z += acc1.z + acc2.z + acc3.z;
        acc0.w += acc1.w + acc2.w + acc3.w;

        red4[al][fc] = acc0;
        __syncthreads();

        const bool interior = (se.x >= c0) && (se.y <= c1);
        if (tid < NFEA) {
            const float* redf = (const float*)red4;   // [8][128]
            float ssum = 0.f;
            #pragma unroll
            for (int g = 0; g < 8; ++g) ssum += redf[g * NFEA + tid];
            if (interior) pooledA[tid] = ssum;
            else          atomicAdd(&seg_sum[(size_t)s * NFEA + tid], ssum);
        }
        __syncthreads();   // red4 free; pooledA published

        if (interior && tid < 64) {
            // wave 0 finalizes while waves 1-3 prefetch the next run;
            // pooledA is only rewritten after the NEXT __syncthreads().
            const float inv_len = 1.f / (float)(se.y - se.x);
            finalize_crystal(tid, s, pooledA[tid] * inv_len, pooledA[tid + 64] * inv_len,
                             lnw, lnb, outw, outb, out_cls, out_act);
        }
        rs = re; ++s;
    }
}

// Kernel B: finalize only boundary-straddling crystals (~n_chunks of them).
__global__ __launch_bounds__(256) void straddler_kernel(
    const float* __restrict__ seg_sum,
    const int2*  __restrict__ idx,
    const float* __restrict__ lnw, const float* __restrict__ lnb,
    const float* __restrict__ outw, const float* __restrict__ outb,
    float* __restrict__ out_cls, float* __restrict__ out_act,
    int n_crys)
{
    const int c    = (blockIdx.x * 256 + threadIdx.x) >> 6;
    const int lane = threadIdx.x & 63;
    if (c >= n_crys) return;
    const int2 se = idx[c];
    if ((se.x / CHUNK) == ((se.y - 1) / CHUNK)) return;   // interior: done in A

    const float inv_len = 1.f / (float)(se.y - se.x);
    const float p0 = seg_sum[(size_t)c * NFEA + lane]      * inv_len;
    const float p1 = seg_sum[(size_t)c * NFEA + lane + 64] * inv_len;
    finalize_crystal(lane, c, p0, p1, lnw, lnb, outw, outb, out_cls, out_act);
}

extern "C" void kernel_launch(void* const* d_in, const int* in_sizes, int n_in,
                              void* d_out, int out_size, void* d_ws, size_t ws_size,
                              hipStream_t stream) {
    const float* fea  = (const float*)d_in[0];   // [1048576][128] f32
    const int2*  idx  = (const int2*)d_in[1];    // [8192][2] i32
    const float* lnw  = (const float*)d_in[2];
    const float* lnb  = (const float*)d_in[3];
    const float* outw = (const float*)d_in[4];
    const float* outb = (const float*)d_in[5];

    const int n_crys  = in_sizes[1] / 2;         // 8192
    const int n_atoms = in_sizes[0] / NFEA;      // 1048576

    float* seg_sum = (float*)d_ws;               // [n_crys][128]
    float* out_cls = (float*)d_out;                          // 8192*5
    float* out_act = (float*)d_out + (size_t)n_crys * NCLS;  // 8192*128

    hipMemsetAsync(seg_sum, 0, (size_t)n_crys * NFEA * sizeof(float), stream);

    fused_pool_kernel<<<n_atoms / CHUNK, 256, 0, stream>>>(
        fea, idx, seg_sum, lnw, lnb, outw, outb, out_cls, out_act, n_crys);

    straddler_kernel<<<(n_crys * 64 + 255) / 256, 256, 0, stream>>>(
        seg_sum, idx, lnw, lnb, outw, outb, out_cls, out_act, n_crys);
}

// Round 5
// 140.638 us; speedup vs baseline: 1.1044x; 1.1044x over previous
//
#include <hip/hip_runtime.h>
#include <hip/hip_bf16.h>

#define NFEA 128
#define NCLS 5
#define LN_EPS 1e-5f
#define SLAB 128   // atoms per independent wave-slab

typedef float f32x4 __attribute__((ext_vector_type(4)));

// LN -> softplus -> head for one crystal, float4-register layout:
// every lane holds features [4*fc, 4*fc+4) of the pooled vector (fc = lane&31,
// both 32-halves redundant). Pure wave-local: shfl reduces, no LDS, no barrier.
__device__ __forceinline__ void finalize_vec(
    int lane, int fc, int c, f32x4 sum, float inv_len,
    const float* __restrict__ lnw, const float* __restrict__ lnb,
    const float* __restrict__ outw, const float* __restrict__ outb,
    float* __restrict__ out_cls, float* __restrict__ out_act)
{
    f32x4 p;
    p[0] = sum[0] * inv_len; p[1] = sum[1] * inv_len;
    p[2] = sum[2] * inv_len; p[3] = sum[3] * inv_len;

    float t = p[0] + p[1] + p[2] + p[3];
    #pragma unroll
    for (int off = 16; off; off >>= 1) t += __shfl_xor(t, off);
    const float mu = t * (1.f / NFEA);

    f32x4 d;
    d[0] = p[0] - mu; d[1] = p[1] - mu; d[2] = p[2] - mu; d[3] = p[3] - mu;
    float v = d[0]*d[0] + d[1]*d[1] + d[2]*d[2] + d[3]*d[3];
    #pragma unroll
    for (int off = 16; off; off >>= 1) v += __shfl_xor(v, off);
    const float rstd = rsqrtf(v * (1.f / NFEA) + LN_EPS);

    const f32x4 w4 = ((const f32x4*)lnw)[fc];
    const f32x4 b4 = ((const f32x4*)lnb)[fc];
    f32x4 act;
    #pragma unroll
    for (int j = 0; j < 4; ++j) {
        const float x = d[j] * rstd * w4[j] + b4[j];
        act[j] = (x > 0.f) ? x + log1pf(expf(-x)) : log1pf(expf(x));
    }
    if (lane < 32) ((f32x4*)out_act)[(size_t)c * 32 + fc] = act;

    #pragma unroll
    for (int k = 0; k < NCLS; ++k) {
        const f32x4 wk = ((const f32x4*)outw)[k * 32 + fc];
        float pk = act[0]*wk[0] + act[1]*wk[1] + act[2]*wk[2] + act[3]*wk[3];
        #pragma unroll
        for (int off = 16; off; off >>= 1) pk += __shfl_xor(pk, off);
        if (lane == k) out_cls[(size_t)c * NCLS + k] = pk + outb[k];
    }
}

// Prep: zero seg_sum (replaces the memset launch) and build slab->segment map.
__global__ __launch_bounds__(256) void prep_kernel(
    const int2* __restrict__ idx,
    int*  __restrict__ seg_of_slab,     // [n_atoms/SLAB]
    float* __restrict__ seg_sum,        // [n_crys][128]
    int n_crys)
{
    const int t    = blockIdx.x * 256 + threadIdx.x;
    const int nthr = gridDim.x * 256;

    f32x4* z = (f32x4*)seg_sum;
    const int nz = n_crys * NFEA / 4;
    for (int i = t; i < nz; i += nthr) z[i] = (f32x4){0.f, 0.f, 0.f, 0.f};

    if (t < n_crys) {
        const int2 se = idx[t];
        int j = (se.x + SLAB - 1) / SLAB;
        for (; j * SLAB < se.y; ++j) seg_of_slab[j] = t;
    }
}

// Main: one independent wave per 128-atom slab. No barriers, no search.
// Nontemporal 16B loads (single-use stream; don't pollute L2). Crystals fully
// inside the slab are finalized wave-locally; straddlers atomicAdd partials.
__global__ __launch_bounds__(256) void main_kernel(
    const float* __restrict__ fea,       // [N_ATOMS][128]
    const int2*  __restrict__ idx,
    const int*   __restrict__ seg_of_slab,
    float* __restrict__ seg_sum,
    const float* __restrict__ lnw, const float* __restrict__ lnb,
    const float* __restrict__ outw, const float* __restrict__ outb,
    float* __restrict__ out_cls, float* __restrict__ out_act)
{
    const int gw   = (blockIdx.x * 256 + threadIdx.x) >> 6;  // wave id = slab id
    const int lane = threadIdx.x & 63;
    const int fc   = lane & 31;
    const int al   = lane >> 5;
    const int a0   = gw * SLAB;
    const int a1   = a0 + SLAB;

    int s = seg_of_slab[gw];
    const f32x4* __restrict__ fea4 = (const f32x4*)fea;

    int rs = a0;
    while (rs < a1) {
        const int2 se = idx[s];
        const int re = min(se.y, a1);

        f32x4 acc0 = {0.f,0.f,0.f,0.f};
        f32x4 acc1 = {0.f,0.f,0.f,0.f};
        f32x4 acc2 = {0.f,0.f,0.f,0.f};
        f32x4 acc3 = {0.f,0.f,0.f,0.f};

        int a = rs + al;
        if (a + 6 < re) {
            f32x4 v0 = __builtin_nontemporal_load(fea4 + (size_t)a       * 32 + fc);
            f32x4 v1 = __builtin_nontemporal_load(fea4 + (size_t)(a + 2) * 32 + fc);
            f32x4 v2 = __builtin_nontemporal_load(fea4 + (size_t)(a + 4) * 32 + fc);
            f32x4 v3 = __builtin_nontemporal_load(fea4 + (size_t)(a + 6) * 32 + fc);
            a += 8;
            for (; a + 6 < re; a += 8) {
                f32x4 n0 = __builtin_nontemporal_load(fea4 + (size_t)a       * 32 + fc);
                f32x4 n1 = __builtin_nontemporal_load(fea4 + (size_t)(a + 2) * 32 + fc);
                f32x4 n2 = __builtin_nontemporal_load(fea4 + (size_t)(a + 4) * 32 + fc);
                f32x4 n3 = __builtin_nontemporal_load(fea4 + (size_t)(a + 6) * 32 + fc);
                acc0 += v0; acc1 += v1; acc2 += v2; acc3 += v3;
                v0 = n0; v1 = n1; v2 = n2; v3 = n3;
            }
            acc0 += v0; acc1 += v1; acc2 += v2; acc3 += v3;
        }
        for (; a < re; a += 2)
            acc0 += __builtin_nontemporal_load(fea4 + (size_t)a * 32 + fc);

        f32x4 accT = acc0 + acc1;
        accT += acc2; accT += acc3;

        // fold the two atom-lanes (lane ^ 32): both halves end with the total
        accT[0] += __shfl_xor(accT[0], 32);
        accT[1] += __shfl_xor(accT[1], 32);
        accT[2] += __shfl_xor(accT[2], 32);
        accT[3] += __shfl_xor(accT[3], 32);

        const bool interior = (se.x >= a0) && (se.y <= a1);
        if (interior) {
            finalize_vec(lane, fc, s, accT, 1.f / (float)(se.y - se.x),
                         lnw, lnb, outw, outb, out_cls, out_act);
        } else if (lane < 32) {
            float* dst = &seg_sum[(size_t)s * NFEA + fc * 4];
            atomicAdd(dst + 0, accT[0]);
            atomicAdd(dst + 1, accT[1]);
            atomicAdd(dst + 2, accT[2]);
            atomicAdd(dst + 3, accT[3]);
        }
        rs = re; ++s;
    }
}

// Cleanup: one wave per crystal; only slab-straddling crystals do work.
__global__ __launch_bounds__(256) void cleanup_kernel(
    const float* __restrict__ seg_sum,
    const int2*  __restrict__ idx,
    const float* __restrict__ lnw, const float* __restrict__ lnb,
    const float* __restrict__ outw, const float* __restrict__ outb,
    float* __restrict__ out_cls, float* __restrict__ out_act,
    int n_crys)
{
    const int c    = (blockIdx.x * 256 + threadIdx.x) >> 6;
    const int lane = threadIdx.x & 63;
    if (c >= n_crys) return;
    const int2 se = idx[c];
    if ((se.x / SLAB) == ((se.y - 1) / SLAB)) return;   // finalized in main

    const int fc = lane & 31;
    const f32x4 sum = ((const f32x4*)seg_sum)[(size_t)c * 32 + fc];
    finalize_vec(lane, fc, c, sum, 1.f / (float)(se.y - se.x),
                 lnw, lnb, outw, outb, out_cls, out_act);
}

extern "C" void kernel_launch(void* const* d_in, const int* in_sizes, int n_in,
                              void* d_out, int out_size, void* d_ws, size_t ws_size,
                              hipStream_t stream) {
    const float* fea  = (const float*)d_in[0];   // [1048576][128] f32
    const int2*  idx  = (const int2*)d_in[1];    // [8192][2] i32
    const float* lnw  = (const float*)d_in[2];
    const float* lnb  = (const float*)d_in[3];
    const float* outw = (const float*)d_in[4];
    const float* outb = (const float*)d_in[5];

    const int n_crys  = in_sizes[1] / 2;         // 8192
    const int n_atoms = in_sizes[0] / NFEA;      // 1048576
    const int nslab   = n_atoms / SLAB;          // 8192

    float* seg_sum     = (float*)d_ws;                                   // 4 MB
    int*   seg_of_slab = (int*)((char*)d_ws + (size_t)n_crys * NFEA * sizeof(float));

    float* out_cls = (float*)d_out;                          // 8192*5
    float* out_act = (float*)d_out + (size_t)n_crys * NCLS;  // 8192*128

    prep_kernel<<<256, 256, 0, stream>>>(idx, seg_of_slab, seg_sum, n_crys);
    main_kernel<<<nslab / 4, 256, 0, stream>>>(fea, idx, seg_of_slab, seg_sum,
                                               lnw, lnb, outw, outb, out_cls, out_act);
    cleanup_kernel<<<(n_crys + 3) / 4, 256, 0, stream>>>(seg_sum, idx, lnw, lnb,
                                                         outw, outb, out_cls, out_act,
                                                         n_crys);
}

// Round 6
// 133.268 us; speedup vs baseline: 1.1655x; 1.0553x over previous
//
#include <hip/hip_runtime.h>
#include <hip/hip_bf16.h>

#define NFEA 128
#define NCLS 5
#define LN_EPS 1e-5f
#define CHUNK 256   // atoms per block-owned chunk

typedef float f32x4 __attribute__((ext_vector_type(4)));

// LN -> softplus -> head, register-f32x4 layout (validated in R5):
// lane holds features [4*fc, 4*fc+4); both 32-lane halves redundant.
__device__ __forceinline__ void finalize_vec(
    int lane, int fc, int c, f32x4 sum, float inv_len,
    const float* __restrict__ lnw, const float* __restrict__ lnb,
    const float* __restrict__ outw, const float* __restrict__ outb,
    float* __restrict__ out_cls, float* __restrict__ out_act)
{
    f32x4 p;
    p[0] = sum[0] * inv_len; p[1] = sum[1] * inv_len;
    p[2] = sum[2] * inv_len; p[3] = sum[3] * inv_len;

    float t = p[0] + p[1] + p[2] + p[3];
    #pragma unroll
    for (int off = 16; off; off >>= 1) t += __shfl_xor(t, off);
    const float mu = t * (1.f / NFEA);

    f32x4 d;
    d[0] = p[0] - mu; d[1] = p[1] - mu; d[2] = p[2] - mu; d[3] = p[3] - mu;
    float v = d[0]*d[0] + d[1]*d[1] + d[2]*d[2] + d[3]*d[3];
    #pragma unroll
    for (int off = 16; off; off >>= 1) v += __shfl_xor(v, off);
    const float rstd = rsqrtf(v * (1.f / NFEA) + LN_EPS);

    const f32x4 w4 = ((const f32x4*)lnw)[fc];
    const f32x4 b4 = ((const f32x4*)lnb)[fc];
    f32x4 act;
    #pragma unroll
    for (int j = 0; j < 4; ++j) {
        const float x = d[j] * rstd * w4[j] + b4[j];
        act[j] = (x > 0.f) ? x + log1pf(expf(-x)) : log1pf(expf(x));
    }
    if (lane < 32) ((f32x4*)out_act)[(size_t)c * 32 + fc] = act;

    #pragma unroll
    for (int k = 0; k < NCLS; ++k) {
        const f32x4 wk = ((const f32x4*)outw)[k * 32 + fc];
        float pk = act[0]*wk[0] + act[1]*wk[1] + act[2]*wk[2] + act[3]*wk[3];
        #pragma unroll
        for (int off = 16; off; off >>= 1) pk += __shfl_xor(pk, off);
        if (lane == k) out_cls[(size_t)c * NCLS + k] = pk + outb[k];
    }
}

// Prep: zero seg_sum (replaces memset launch) + chunk -> first-segment map
// (replaces the per-block binary search).
__global__ __launch_bounds__(256) void prep_kernel(
    const int2* __restrict__ idx,
    int*  __restrict__ seg_of_chunk,    // [n_atoms/CHUNK]
    float* __restrict__ seg_sum,        // [n_crys][128]
    int n_crys)
{
    const int t    = blockIdx.x * 256 + threadIdx.x;
    const int nthr = gridDim.x * 256;

    f32x4* z = (f32x4*)seg_sum;
    const int nz = n_crys * NFEA / 4;
    for (int i = t; i < nz; i += nthr) z[i] = (f32x4){0.f, 0.f, 0.f, 0.f};

    if (t < n_crys) {
        const int2 se = idx[t];
        int j = (se.x + CHUNK - 1) / CHUNK;
        for (; j * CHUNK < se.y; ++j) seg_of_chunk[j] = t;
    }
}

// Main: block streams its 256-atom chunk with a 4-deep, 8-lane-stride loader
// (16KB contiguous in flight). Per run: LDS 8->1 reduce, atomicAdd partials.
__global__ __launch_bounds__(256) void seg_sum_kernel(
    const float* __restrict__ fea,       // [N_ATOMS][128]
    const int2*  __restrict__ idx,
    const int*   __restrict__ seg_of_chunk,
    float* __restrict__ seg_sum)
{
    const int c0 = blockIdx.x * CHUNK;
    const int c1 = c0 + CHUNK;
    const int tid = threadIdx.x;
    const int fc  = tid & 31;
    const int al  = tid >> 5;

    int s = seg_of_chunk[blockIdx.x];
    const f32x4* __restrict__ fea4 = (const f32x4*)fea;
    __shared__ f32x4 red4[8][32];

    int rs = c0;
    while (rs < c1) {
        const int re = min(idx[s].y, c1);

        f32x4 acc0 = {0.f,0.f,0.f,0.f};
        f32x4 acc1 = {0.f,0.f,0.f,0.f};
        f32x4 acc2 = {0.f,0.f,0.f,0.f};
        f32x4 acc3 = {0.f,0.f,0.f,0.f};

        int a = rs + al;
        if (a + 24 < re) {
            f32x4 v0 = fea4[(size_t)a        * 32 + fc];
            f32x4 v1 = fea4[(size_t)(a + 8)  * 32 + fc];
            f32x4 v2 = fea4[(size_t)(a + 16) * 32 + fc];
            f32x4 v3 = fea4[(size_t)(a + 24) * 32 + fc];
            a += 32;
            for (; a + 24 < re; a += 32) {
                f32x4 n0 = fea4[(size_t)a        * 32 + fc];
                f32x4 n1 = fea4[(size_t)(a + 8)  * 32 + fc];
                f32x4 n2 = fea4[(size_t)(a + 16) * 32 + fc];
                f32x4 n3 = fea4[(size_t)(a + 24) * 32 + fc];
                acc0 += v0; acc1 += v1; acc2 += v2; acc3 += v3;
                v0 = n0; v1 = n1; v2 = n2; v3 = n3;
            }
            acc0 += v0; acc1 += v1; acc2 += v2; acc3 += v3;
        }
        for (; a < re; a += 8)
            acc0 += fea4[(size_t)a * 32 + fc];

        f32x4 accT = (acc0 + acc1) + (acc2 + acc3);

        red4[al][fc] = accT;
        __syncthreads();
        if (tid < NFEA) {
            const float* redf = (const float*)red4;   // [8][128]
            float ssum = 0.f;
            #pragma unroll
            for (int g = 0; g < 8; ++g) ssum += redf[g * NFEA + tid];
            atomicAdd(&seg_sum[(size_t)s * NFEA + tid], ssum);
        }
        __syncthreads();
        rs = re; ++s;
    }
}

// Finalize: 4 crystals per 256-thread block, one wave each.
__global__ __launch_bounds__(256) void finalize_kernel(
    const float* __restrict__ seg_sum,
    const int2*  __restrict__ idx,
    const float* __restrict__ lnw, const float* __restrict__ lnb,
    const float* __restrict__ outw, const float* __restrict__ outb,
    float* __restrict__ out_cls, float* __restrict__ out_act,
    int n_crys)
{
    const int c    = (blockIdx.x * 256 + threadIdx.x) >> 6;
    const int lane = threadIdx.x & 63;
    if (c >= n_crys) return;
    const int2 se = idx[c];
    const int fc = lane & 31;
    const f32x4 sum = ((const f32x4*)seg_sum)[(size_t)c * 32 + fc];
    finalize_vec(lane, fc, c, sum, 1.f / (float)(se.y - se.x),
                 lnw, lnb, outw, outb, out_cls, out_act);
}

extern "C" void kernel_launch(void* const* d_in, const int* in_sizes, int n_in,
                              void* d_out, int out_size, void* d_ws, size_t ws_size,
                              hipStream_t stream) {
    const float* fea  = (const float*)d_in[0];   // [1048576][128] f32
    const int2*  idx  = (const int2*)d_in[1];    // [8192][2] i32
    const float* lnw  = (const float*)d_in[2];
    const float* lnb  = (const float*)d_in[3];
    const float* outw = (const float*)d_in[4];
    const float* outb = (const float*)d_in[5];

    const int n_crys  = in_sizes[1] / 2;         // 8192
    const int n_atoms = in_sizes[0] / NFEA;      // 1048576
    const int nchunk  = n_atoms / CHUNK;         // 4096

    float* seg_sum      = (float*)d_ws;                                   // 4 MB
    int*   seg_of_chunk = (int*)((char*)d_ws + (size_t)n_crys * NFEA * sizeof(float));

    float* out_cls = (float*)d_out;                          // 8192*5
    float* out_act = (float*)d_out + (size_t)n_crys * NCLS;  // 8192*128

    prep_kernel<<<256, 256, 0, stream>>>(idx, seg_of_chunk, seg_sum, n_crys);
    seg_sum_kernel<<<nchunk, 256, 0, stream>>>(fea, idx, seg_of_chunk, seg_sum);
    finalize_kernel<<<(n_crys + 3) / 4, 256, 0, stream>>>(
        seg_sum, idx, lnw, lnb, outw, outb, out_cls, out_act, n_crys);
}